// Round 12
// baseline (188.976 us; speedup 1.0000x reference)
//
#include <hip/hip_runtime.h>
#include <hip/hip_fp16.h>

typedef _Float16 half8  __attribute__((ext_vector_type(8)));
typedef _Float16 half4_t __attribute__((ext_vector_type(4)));
typedef _Float16 half2_t __attribute__((ext_vector_type(2)));
typedef float f32x4 __attribute__((ext_vector_type(4)));

namespace {
constexpr int NT = 384;            // 6 waves; LDS-bound at 3 blocks/CU -> 18 waves/CU
constexpr int NPIX = 225;
constexpr int PCODE_C = 2380;

// A_pad[6][17][17] half8 slots: row pitch 272 B, cg pitch 4624 B
constexpr int APITCH_Y  = 272;
constexpr int APITCH_CG = 4624;
constexpr int XPITCH    = 96;      // X row pitch (48 f16)

// ---- LDS layout (byte offsets) -- R7-proven: X separate, PolA aliases dead A ----
constexpr int OFF_A     = 0;       // A_pad 27744 (dead after P2; PolA_pad 9248 aliases @0)
constexpr int OFF_POLA  = 0;
constexpr int OFF_X     = 27744;   // [240 rows][96 B] = 23040 (rows 225+ garbage, discarded)
constexpr int OFF_WC    = 50784;   // dw conv w  f16 [6][9][8]  = 864
constexpr int OFF_WCB   = 51648;   // dw conv b  f16 [6][8]     = 96
constexpr int OFF_WPD   = 51744;   // pol dw w   f16 [2][9][8]  = 288
constexpr int OFF_WPDB  = 52032;   // pol dw b   f16 [2][8]     = 32
constexpr int OFF_SV    = 52064;   // f32[32] = 128
constexpr int OFF_H1    = 52192;   // f32[32] = 128
constexpr int OFF_H2    = 52320;   // f32[32] = 128
constexpr int SMEM_BYTES = 52448;  // 3 blocks/CU (157344 < 163840)
}

__device__ __forceinline__ half2_t pkrtz(float a, float b) {
    return __builtin_bit_cast(half2_t, __builtin_amdgcn_cvt_pkrtz(a, b));
}
__device__ __forceinline__ void wave_fence() {
    asm volatile("s_waitcnt lgkmcnt(0)" ::: "memory");
}

__global__ __launch_bounds__(NT, 4) void patnet_kernel(
    const float* __restrict__ emb,
    const float* __restrict__ conv_w, const float* __restrict__ conv_b,
    const float* __restrict__ ppw_w,  const float* __restrict__ ppw_b,
    const float* __restrict__ pdw_w,  const float* __restrict__ pdw_b,
    const float* __restrict__ pf_w,
    const float* __restrict__ vpw_w,  const float* __restrict__ vpw_b,
    const float* __restrict__ vl1_w,  const float* __restrict__ vl1_b,
    const float* __restrict__ vl2_w,  const float* __restrict__ vl2_b,
    const float* __restrict__ vf_w,   const float* __restrict__ vf_b,
    const int* __restrict__ sparse,   const int* __restrict__ board,
    float* __restrict__ out, int batch)
{
    __shared__ __align__(16) unsigned char smem[SMEM_BYTES];
    const int tid  = threadIdx.x;
    const int b    = blockIdx.x;
    const int lane = tid & 63;
    const int wave = tid >> 6;

    // ---- issue code loads first (deep prefetch) ----
    int c0 = 0, c1 = 0;
    if (tid < NPIX) {
        int s10 = sparse[b * 2700 + 10 * NPIX + tid];
        int s11 = sparse[b * 2700 + 11 * NPIX + tid];
        int b0  = board[b * 450 + tid];
        int b1  = board[b * 450 + NPIX + tid];
        c0 = (b0 > 0) ? PCODE_C : s10;
        c1 = ((b1 > 0) ? PCODE_C : s11) + (PCODE_C + 1);
    }

    // ---- P0: stage depthwise weight tables (transposed) + zero A pads ----
    {
        _Float16* Wc   = (_Float16*)(smem + OFF_WC);
        _Float16* Wcb  = (_Float16*)(smem + OFF_WCB);
        _Float16* Wpd  = (_Float16*)(smem + OFF_WPD);
        _Float16* Wpdb = (_Float16*)(smem + OFF_WPDB);
        for (int i = tid; i < 432; i += NT) {     // Wc[cg][tap][j] = conv_w[(cg*8+j)*9+tap]
            int cg = i / 72, rem = i - cg * 72;
            int t = rem >> 3, j = rem & 7;
            Wc[i] = (_Float16)conv_w[(cg * 8 + j) * 9 + t];
        }
        for (int i = tid; i < 48; i += NT) Wcb[i] = (_Float16)conv_b[i];
        for (int i = tid; i < 144; i += NT) {
            int cg = i / 72, rem = i - cg * 72;
            int t = rem >> 3, j = rem & 7;
            Wpd[i] = (_Float16)pdw_w[(cg * 8 + j) * 9 + t];
        }
        for (int i = tid; i < 16; i += NT) Wpdb[i] = (_Float16)pdw_b[i];
        // zero A_pad borders: 64 slots per cg
        for (int i = tid; i < 384; i += NT) {
            int cg = i >> 6, j = i & 63;
            int row, col;
            if (j < 17)      { row = 0;  col = j; }
            else if (j < 34) { row = 16; col = j - 17; }
            else { int k = j - 34; row = 1 + (k >> 1); col = (k & 1) * 16; }
            *(half8*)(smem + OFF_A + cg * APITCH_CG + row * APITCH_Y + col * 16) = (half8)(_Float16)0.f;
        }
    }

    // ---- P1: embedding gather + sum -> A_pad interior ----
    if (tid < NPIX) {
        const float* e0 = emb + c0 * 48;
        const float* e1 = emb + c1 * 48;
        int y = tid / 15, x = tid - y * 15;
        unsigned char* abase = smem + OFF_A + (y + 1) * APITCH_Y + (x + 1) * 16;
        #pragma unroll
        for (int g = 0; g < 6; g++) {
            f32x4 x0 = *(const f32x4*)(e0 + g * 8);
            f32x4 x1 = *(const f32x4*)(e0 + g * 8 + 4);
            f32x4 y0 = *(const f32x4*)(e1 + g * 8);
            f32x4 y1 = *(const f32x4*)(e1 + g * 8 + 4);
            f32x4 s0 = x0 + y0, s1 = x1 + y1;
            half2_t q0 = pkrtz(s0.x, s0.y), q1 = pkrtz(s0.z, s0.w);
            half2_t q2 = pkrtz(s1.x, s1.y), q3 = pkrtz(s1.z, s1.w);
            half8 hv = {q0[0], q0[1], q1[0], q1[1], q2[0], q2[1], q3[0], q3[1]};
            *(half8*)(abase + g * APITCH_CG) = hv;
        }
    }
    __syncthreads();                               // B1

    // ---- P2: depthwise 3x3 via 5-px strips (270 tasks, one per thread), write X ----
    if (tid < 270) {
        int t = tid;
        int cg = t / 45, rem = t - cg * 45;
        int y = rem / 3, s = rem - y * 3;
        int xs = s * 5;
        const unsigned char* wb = smem + OFF_WC + cg * 144;
        half8 wv[9];
        #pragma unroll
        for (int i = 0; i < 9; i++) wv[i] = *(const half8*)(wb + i * 16);
        half8 bias = *(const half8*)(smem + OFF_WCB + cg * 16);
        half8 acc[5] = {bias, bias, bias, bias, bias};
        const unsigned char* ab = smem + OFF_A + cg * APITCH_CG + y * APITCH_Y + xs * 16;
        #pragma unroll
        for (int c = 0; c < 7; c++) {
            half8 v0 = *(const half8*)(ab + c * 16);
            half8 v1 = *(const half8*)(ab + APITCH_Y + c * 16);
            half8 v2 = *(const half8*)(ab + 2 * APITCH_Y + c * 16);
            #pragma unroll
            for (int o = 0; o < 5; o++) {
                int kx = c - o;
                if (kx >= 0 && kx <= 2) {
                    acc[o] = __builtin_elementwise_fma(v0, wv[kx],     acc[o]);
                    acc[o] = __builtin_elementwise_fma(v1, wv[3 + kx], acc[o]);
                    acc[o] = __builtin_elementwise_fma(v2, wv[6 + kx], acc[o]);
                }
            }
        }
        unsigned char* xw = smem + OFF_X + (y * 15 + xs) * XPITCH + cg * 16;
        #pragma unroll
        for (int o = 0; o < 5; o++)
            *(half8*)(xw + o * XPITCH) = __builtin_elementwise_max(acc[o], (half8)(_Float16)0.f);
    }

    // ---- head-weight prep by ALL waves (loads fly during barrier drain) ----
    const int n = lane & 15, q = lane >> 4;
    half8 af_p;
    {
        const float* wp = ppw_w + n * 16 + (q & 1) * 8;
        f32x4 w0 = *(const f32x4*)wp, w1 = *(const f32x4*)(wp + 4);
        half8 t = {(_Float16)w0.x, (_Float16)w0.y, (_Float16)w0.z, (_Float16)w0.w,
                   (_Float16)w1.x, (_Float16)w1.y, (_Float16)w1.z, (_Float16)w1.w};
        af_p = (q < 2) ? t : (half8)(_Float16)0.f;   // K zero-pad 16..31
    }
    f32x4 pb = *(const f32x4*)(ppw_b + q * 4);
    const int cgp = lane & 1;
    // pf as NAMED regs (no runtime-indexed local array)
    const float* pfb = pf_w + cgp * 8;
    half2_t pf0 = pkrtz(pfb[0], pfb[1]);
    half2_t pf1 = pkrtz(pfb[2], pfb[3]);
    half2_t pf2 = pkrtz(pfb[4], pfb[5]);
    half2_t pf3 = pkrtz(pfb[6], pfb[7]);
    // value-head A-frag for this wave's oc-half (waves 4,5; harmless elsewhere)
    const int vh = wave - 4;                        // 0 or 1 for value waves
    const int vsel = (vh == 1) ? 16 : 0;
    half8 af_v;
    {
        const float* wp = vpw_w + (vsel + n) * 32 + q * 8;
        f32x4 w0 = *(const f32x4*)wp, w1 = *(const f32x4*)(wp + 4);
        af_v = half8{(_Float16)w0.x, (_Float16)w0.y, (_Float16)w0.z, (_Float16)w0.w,
                     (_Float16)w1.x, (_Float16)w1.y, (_Float16)w1.z, (_Float16)w1.w};
    }
    f32x4 vb = *(const f32x4*)(vpw_b + vsel + q * 4);
    __syncthreads();                               // B2

    // ================= head split (no block barrier until B3) =================
    if (wave < 4) {
        // ---------------- policy path (waves 0..3) ----------------
        // zero PolA pads (aliases dead A; idempotent across policy waves)
        #pragma unroll
        for (int i0 = 0; i0 < 2; i0++) {
            int i = i0 * 64 + lane;
            int cg = i >> 6, j = i & 63;
            int row, col;
            if (j < 17)      { row = 0;  col = j; }
            else if (j < 34) { row = 16; col = j - 17; }
            else { int k = j - 34; row = 1 + (k >> 1); col = (k & 1) * 16; }
            *(half8*)(smem + OFF_POLA + cg * APITCH_CG + row * APITCH_Y + col * 16) = (half8)(_Float16)0.f;
        }
        half8 wvp[9];
        #pragma unroll
        for (int t = 0; t < 9; t++) wvp[t] = *(const half8*)(smem + OFF_WPD + cgp * 144 + t * 16);
        half8 biasp = *(const half8*)(smem + OFF_WPDB + cgp * 16);

        // ph3: 1x1 16->16 via MFMA; wave computes every tile its ph4 rows need
        // wave w owns output px [60w, 60w+60) (w=3: 45); halo tiles:
        const int tlo = (wave == 0) ? 0 : (wave == 1) ? 2 : (wave == 2) ? 6 : 10;
        const int thi = (wave == 0) ? 5 : (wave == 1) ? 9 : (wave == 2) ? 13 : 15;
        const int cg3 = q >> 1;
        for (int t = tlo; t < thi; t++) {
            int p = t * 16 + n;
            half8 bf = *(const half8*)(smem + OFF_X + p * XPITCH + q * 16);
            f32x4 d = __builtin_amdgcn_mfma_f32_16x16x32_f16(af_p, bf, (f32x4)(0.f), 0, 0, 0);
            if (p < NPIX) {
                int y = p / 15, x = p - y * 15;
                half2_t lo = pkrtz(fmaxf(d.x + pb.x, 0.f), fmaxf(d.y + pb.y, 0.f));
                half2_t hi = pkrtz(fmaxf(d.z + pb.z, 0.f), fmaxf(d.w + pb.w, 0.f));
                half4_t hv = {lo[0], lo[1], hi[0], hi[1]};
                *(half4_t*)(smem + OFF_POLA + cg3 * APITCH_CG + (y + 1) * APITCH_Y + (x + 1) * 16 + (q & 1) * 8) = hv;
            }
        }
        wave_fence();

        // ph4+ph5 fused: dw 3x3 + bias + relu + dot(pf) + pair-sum + store
        const int px0 = wave * 60;
        const int cnt2 = ((wave == 3) ? 45 : 60) * 2;
        #pragma unroll
        for (int i = 0; i < 2; i++) {
            int idx = i * 64 + lane;
            if (idx < cnt2) {
                int px = px0 + (idx >> 1);
                int y = px / 15, x = px - y * 15;
                const unsigned char* pbse = smem + OFF_POLA + cgp * APITCH_CG + y * APITCH_Y + x * 16;
                half8 acc = biasp;
                #pragma unroll
                for (int ky = 0; ky < 3; ky++) {
                    acc = __builtin_elementwise_fma(*(const half8*)(pbse + ky * APITCH_Y),      wvp[ky * 3 + 0], acc);
                    acc = __builtin_elementwise_fma(*(const half8*)(pbse + ky * APITCH_Y + 16), wvp[ky * 3 + 1], acc);
                    acc = __builtin_elementwise_fma(*(const half8*)(pbse + ky * APITCH_Y + 32), wvp[ky * 3 + 2], acc);
                }
                acc = __builtin_elementwise_max(acc, (half8)(_Float16)0.f);
                float part = 0.f;
                part = __builtin_amdgcn_fdot2(half2_t{acc[0], acc[1]}, pf0, part, false);
                part = __builtin_amdgcn_fdot2(half2_t{acc[2], acc[3]}, pf1, part, false);
                part = __builtin_amdgcn_fdot2(half2_t{acc[4], acc[5]}, pf2, part, false);
                part = __builtin_amdgcn_fdot2(half2_t{acc[6], acc[7]}, pf3, part, false);
                float tot = part + __shfl_xor(part, 1, 64);
                if (cgp == 0) out[3 * batch + b * NPIX + px] = tot;
            }
        }
    } else {
        // ---------------- value path (waves 4,5: oc-halves) ----------------
        f32x4 a0 = {0.f, 0.f, 0.f, 0.f};
        for (int t = 0; t < 15; t++) {
            int p = t * 16 + n;
            half8 bf = *(const half8*)(smem + OFF_X + p * XPITCH + 32 + q * 16);
            f32x4 d = __builtin_amdgcn_mfma_f32_16x16x32_f16(af_v, bf, (f32x4)(0.f), 0, 0, 0);
            if (p < NPIX) {
                #pragma unroll
                for (int r = 0; r < 4; r++)
                    a0[r] += fmaxf(d[r] + vb[r], 0.f);
            }
        }
        #pragma unroll
        for (int s = 1; s < 16; s <<= 1) {
            #pragma unroll
            for (int r = 0; r < 4; r++)
                a0[r] += __shfl_xor(a0[r], s, 64);
        }
        if (n == 0)
            *(f32x4*)(smem + OFF_SV + vsel * 4 + q * 16) = a0 * (1.f / 225.f);
    }
    __syncthreads();                               // B3: s_v complete, policy done

    // ---- FC tail on wave 0 (lanes 0..31) ----
    if (wave == 0 && lane < 32) {
        const int o = lane;
        float acc1f = vl1_b[o];
        #pragma unroll
        for (int g = 0; g < 8; g++) {
            f32x4 sv = *(const f32x4*)(smem + OFF_SV + g * 16);
            f32x4 w4 = *(const f32x4*)(vl1_w + o * 32 + g * 4);
            acc1f += sv.x * w4.x + sv.y * w4.y + sv.z * w4.z + sv.w * w4.w;
        }
        acc1f = fmaxf(acc1f, 0.f);
        *(float*)(smem + OFF_H1 + o * 4) = acc1f;
        wave_fence();

        float acc2f = vl2_b[o];
        #pragma unroll
        for (int g = 0; g < 8; g++) {
            f32x4 hv = *(const f32x4*)(smem + OFF_H1 + g * 16);
            f32x4 w4 = *(const f32x4*)(vl2_w + o * 32 + g * 4);
            acc2f += hv.x * w4.x + hv.y * w4.y + hv.z * w4.z + hv.w * w4.w;
        }
        acc2f = fmaxf(acc2f, 0.f);
        *(float*)(smem + OFF_H2 + o * 4) = acc2f;
        wave_fence();

        if (lane < 3) {
            float acc3f = vf_b[lane];
            #pragma unroll
            for (int g = 0; g < 8; g++) {
                f32x4 hv = *(const f32x4*)(smem + OFF_H2 + g * 16);
                f32x4 w4 = *(const f32x4*)(vf_w + lane * 32 + g * 4);
                acc3f += hv.x * w4.x + hv.y * w4.y + hv.z * w4.z + hv.w * w4.w;
            }
            out[b * 3 + lane] = acc3f;
        }
    }
}

extern "C" void kernel_launch(void* const* d_in, const int* in_sizes, int n_in,
                              void* d_out, int out_size, void* d_ws, size_t ws_size,
                              hipStream_t stream) {
    const float* emb    = (const float*)d_in[0];
    const float* conv_w = (const float*)d_in[1];
    const float* conv_b = (const float*)d_in[2];
    const float* ppw_w  = (const float*)d_in[3];
    const float* ppw_b  = (const float*)d_in[4];
    const float* pdw_w  = (const float*)d_in[5];
    const float* pdw_b  = (const float*)d_in[6];
    const float* pf_w   = (const float*)d_in[7];
    const float* vpw_w  = (const float*)d_in[8];
    const float* vpw_b  = (const float*)d_in[9];
    const float* vl1_w  = (const float*)d_in[10];
    const float* vl1_b  = (const float*)d_in[11];
    const float* vl2_w  = (const float*)d_in[12];
    const float* vl2_b  = (const float*)d_in[13];
    const float* vf_w   = (const float*)d_in[14];
    const float* vf_b   = (const float*)d_in[15];
    const int* sparse   = (const int*)d_in[16];
    const int* board    = (const int*)d_in[17];
    float* out = (float*)d_out;

    int batch = in_sizes[16] / 2700;  // 4096
    patnet_kernel<<<batch, NT, 0, stream>>>(
        emb, conv_w, conv_b, ppw_w, ppw_b, pdw_w, pdw_b, pf_w,
        vpw_w, vpw_b, vl1_w, vl1_b, vl2_w, vl2_b, vf_w, vf_b,
        sparse, board, out, batch);
}